// Round 8
// baseline (385.525 us; speedup 1.0000x reference)
//
#include <hip/hip_runtime.h>

// VQ-VAE eval forward, MI355X — R8: qout fused into mega (Phase E reuses the
// dead A-frag LDS as the gather-staging tile; idxout global array removed).
// inputs:  d_in[0] = inputs  fp32 [64,64,32,32] NCHW  (4,194,304)
//          d_in[1] = emb     fp32 [1024,64]           (65,536)
// outputs in d_out (fp32, flat): loss | quantized NCHW (4194304) |
//          perplexity | encodings [65536,1024] (256 MB)
//
// Distance argmin via S = X·E^T with bf16 hi/lo split (3 MFMA terms,
// ~1e-6 abs err vs ~2e-5 code gaps). B-frags parked in the quantized region
// of d_out (dead until Phase E of the same mega block writes it — but each
// block writes only its own 32 KB slab AFTER reading all B-frags into the
// ct-loop stream... NOTE: B-frags are re-read from global THROUGHOUT the ct
// loop, which runs before Phase E of every block; since blocks run
// concurrently, a fast block's Phase E could overwrite frags a slow block
// still needs -> B-frags MUST NOT live in the quantized region anymore.
// They live in ws (correctly sized 128 KB each, R6's bug was sizing).

#define NROWS 65536
#define DIM   64
#define KCB   1024

typedef __attribute__((ext_vector_type(8))) short  short8;
typedef __attribute__((ext_vector_type(4))) float  floatx4;
typedef __attribute__((ext_vector_type(2))) float  floatx2;

__device__ inline unsigned short f2bf(float f) {
    unsigned u = __float_as_uint(f);
    u = u + 0x7fffu + ((u >> 16) & 1u);      // round-to-nearest-even
    return (unsigned short)(u >> 16);
}
__device__ inline float bf2f(unsigned short h) {
    return __uint_as_float(((unsigned)h) << 16);
}

// ---- init: se[k], hist=0, scalars=0, e -> B-fragment-ordered bf16 hi/lo ----
// B-frag layout (16x16x32): elem (ct,kt,lane,j) = emb[code=ct*16+(lane&15)]
//                           [dim=kt*32+(lane>>4)*8+j]
__global__ __launch_bounds__(256) void vq_init_kernel(
    const float* __restrict__ emb, float* __restrict__ se,
    int* __restrict__ hist, float* __restrict__ lossacc, float* __restrict__ sumx2,
    short8* __restrict__ ebh, short8* __restrict__ ebl)
{
    const int code = blockIdx.x * 256 + threadIdx.x;   // 0..1023
    const float* e = emb + (code << 6);
    float s = 0.f;
    float v[DIM];
#pragma unroll
    for (int d = 0; d < DIM; ++d) { v[d] = e[d]; s = fmaf(v[d], v[d], s); }
    se[code] = s;
    hist[code] = 0;
    if (code == 0) { lossacc[0] = 0.f; sumx2[0] = 0.f; }

    const int ct = code >> 4;
#pragma unroll
    for (int jg = 0; jg < 8; ++jg) {                   // dims jg*8 .. jg*8+7
        const int kt   = jg >> 2;
        const int lane = (code & 15) + 16 * (jg & 3);
        short8 h8, l8;
#pragma unroll
        for (int j = 0; j < 8; ++j) {
            float x = v[jg * 8 + j];
            unsigned short h = f2bf(x);
            h8[j] = (short)h;
            l8[j] = (short)f2bf(x - bf2f(h));
        }
        ebh[(ct * 2 + kt) * 64 + lane] = h8;
        ebl[(ct * 2 + kt) * 64 + lane] = l8;
    }
}

// ---- mega: block = 128 rows (one n, one 128-wide hw slab).
//  A: x load + bf16-split -> LDS A-frags.   B: MFMA argmin over 1024 codes.
//  C: idx/hist/loss reduce.                 E: quantized gather+write (reuses
//  the dead frag LDS as a 128x65 staging tile).   D: enc one-hot streaming.
__global__ __launch_bounds__(256) void vq_mega_kernel(
    const float* __restrict__ inp, const short8* __restrict__ ebh,
    const short8* __restrict__ ebl, const float* __restrict__ se,
    const float4* __restrict__ emb4, float* __restrict__ outq,
    int* __restrict__ hist, float* __restrict__ lossacc,
    float* __restrict__ sumx2, floatx2* __restrict__ enc2)
{
    __shared__ union SMem {
        struct { short8 H[1024]; short8 L[1024]; } frag;   // 32 KB (A,B)
        float q[128 * 65];                                 // 33.3 KB (E)
    } sm;
    __shared__ int ks[128];

    const int tid  = threadIdx.x;
    const int rblk = blockIdx.x << 7;        // first row of this block
    const int n    = rblk >> 10;             // 128 | 1024 -> single n per block
    const int hw0  = rblk & 1023;            // 128-aligned

    // ---- Phase A ----
    {
        const int r_loc = tid & 127;
        const int half  = tid >> 7;          // dims half*32 .. +31
        const float* base = inp + n * 65536 + hw0 + r_loc;
        float v[32];
        float s2 = 0.f;
#pragma unroll
        for (int j = 0; j < 32; ++j) {
            v[j] = base[(half * 32 + j) << 10];   // 256 B coalesced per instr
            s2 = fmaf(v[j], v[j], s2);
        }
        const int s16 = r_loc >> 4;
#pragma unroll
        for (int jg2 = 0; jg2 < 4; ++jg2) {       // jg = half*4 + jg2
            short8 h8, l8;
#pragma unroll
            for (int jj = 0; jj < 8; ++jj) {
                float x = v[jg2 * 8 + jj];
                unsigned short h = f2bf(x);
                h8[jj] = (short)h;
                l8[jj] = (short)f2bf(x - bf2f(h));
            }
            // kt = jg>>2 = half; lane = (row&15) + 16*(jg&3), jg&3 = jg2
            int fi = (s16 * 2 + half) * 64 + (r_loc & 15) + (jg2 << 4);
            sm.frag.H[fi] = h8;
            sm.frag.L[fi] = l8;
        }
#pragma unroll
        for (int m = 1; m <= 32; m <<= 1) s2 += __shfl_xor(s2, m, 64);
        if ((tid & 63) == 0) atomicAdd(sumx2, s2);
    }
    __syncthreads();

    // ---- Phase B: MFMA argmin (numerics identical to R5/R7) ----
    const int lane = tid & 63;
    const int wid  = tid >> 6;

    short8 ah[2][2], al[2][2];
#pragma unroll
    for (int s = 0; s < 2; ++s)
#pragma unroll
        for (int kt = 0; kt < 2; ++kt) {
            int fi = ((wid * 2 + s) * 2 + kt) * 64 + lane;
            ah[s][kt] = sm.frag.H[fi];
            al[s][kt] = sm.frag.L[fi];
        }

    float minv[2][4]; int mini[2][4];
#pragma unroll
    for (int s = 0; s < 2; ++s)
#pragma unroll
        for (int r = 0; r < 4; ++r) { minv[s][r] = 3.0e38f; mini[s][r] = 0; }

    const int cl = lane & 15;
    short8 b0h = ebh[lane], b0l = ebl[lane];
    short8 b1h = ebh[64 + lane], b1l = ebl[64 + lane];

    for (int ct = 0; ct < 64; ++ct) {
        short8 ch0 = b0h, cB0 = b0l, ch1 = b1h, cB1 = b1l;
        if (ct < 63) {                         // double-buffer next B-frags
            b0h = ebh[(ct + 1) * 128 + lane];
            b0l = ebl[(ct + 1) * 128 + lane];
            b1h = ebh[(ct + 1) * 128 + 64 + lane];
            b1l = ebl[(ct + 1) * 128 + 64 + lane];
        }
        floatx4 a0 = {0.f, 0.f, 0.f, 0.f};
        floatx4 a1 = {0.f, 0.f, 0.f, 0.f};
        // S = xh*eh + xh*el + xl*eh, fp32 accumulate
        a0 = __builtin_amdgcn_mfma_f32_16x16x32_bf16(ah[0][0], ch0, a0, 0, 0, 0);
        a0 = __builtin_amdgcn_mfma_f32_16x16x32_bf16(ah[0][1], ch1, a0, 0, 0, 0);
        a0 = __builtin_amdgcn_mfma_f32_16x16x32_bf16(ah[0][0], cB0, a0, 0, 0, 0);
        a0 = __builtin_amdgcn_mfma_f32_16x16x32_bf16(ah[0][1], cB1, a0, 0, 0, 0);
        a0 = __builtin_amdgcn_mfma_f32_16x16x32_bf16(al[0][0], ch0, a0, 0, 0, 0);
        a0 = __builtin_amdgcn_mfma_f32_16x16x32_bf16(al[0][1], ch1, a0, 0, 0, 0);
        a1 = __builtin_amdgcn_mfma_f32_16x16x32_bf16(ah[1][0], ch0, a1, 0, 0, 0);
        a1 = __builtin_amdgcn_mfma_f32_16x16x32_bf16(ah[1][1], ch1, a1, 0, 0, 0);
        a1 = __builtin_amdgcn_mfma_f32_16x16x32_bf16(ah[1][0], cB0, a1, 0, 0, 0);
        a1 = __builtin_amdgcn_mfma_f32_16x16x32_bf16(ah[1][1], cB1, a1, 0, 0, 0);
        a1 = __builtin_amdgcn_mfma_f32_16x16x32_bf16(al[1][0], ch0, a1, 0, 0, 0);
        a1 = __builtin_amdgcn_mfma_f32_16x16x32_bf16(al[1][1], ch1, a1, 0, 0, 0);

        const float sel = se[ct * 16 + cl];
        const int  code = ct * 16 + cl;
#pragma unroll
        for (int r = 0; r < 4; ++r) {
            float d0 = fmaf(-2.f, a0[r], sel);
            if (d0 < minv[0][r]) { minv[0][r] = d0; mini[0][r] = code; }
            float d1 = fmaf(-2.f, a1[r], sel);
            if (d1 < minv[1][r]) { minv[1][r] = d1; mini[1][r] = code; }
        }
    }

    // ---- Phase C: reduce (val,idx) across 16 lanes; ks/hist/loss ----
    float lossp = 0.f;
#pragma unroll
    for (int s = 0; s < 2; ++s)
#pragma unroll
        for (int r = 0; r < 4; ++r) {
            float v = minv[s][r]; int i = mini[s][r];
#pragma unroll
            for (int m = 1; m <= 8; m <<= 1) {
                float ov = __shfl_xor(v, m, 64);
                int   oi = __shfl_xor(i, m, 64);
                if (ov < v || (ov == v && oi < i)) { v = ov; i = oi; }
            }
            if ((lane & 15) == 0) {
                int row_loc = wid * 32 + s * 16 + (lane >> 4) * 4 + r;
                ks[row_loc] = i;
                atomicAdd(&hist[i], 1);
                lossp += v;                     // d'_min for this row
            }
        }
#pragma unroll
    for (int m = 1; m <= 32; m <<= 1) lossp += __shfl_xor(lossp, m, 64);
    if (lane == 0) atomicAdd(lossacc, lossp);
    __syncthreads();   // ks valid for all; frag regs long since consumed

    // ---- Phase E: quantized gather -> LDS (pad 65) -> coalesced NT stores
    {
#pragma unroll
        for (int i = 0; i < 8; ++i) {
            int flat = tid + (i << 8);        // 0..2047 = 128 rows x 16 float4
            int hw = flat >> 4;
            int f4 = flat & 15;
            float4 v = emb4[(ks[hw] << 4) + f4];   // 256 B row reads, L2-hot
            float* dst = &sm.q[hw * 65 + (f4 << 2)];
            dst[0] = v.x; dst[1] = v.y; dst[2] = v.z; dst[3] = v.w;
        }
        __syncthreads();
        const int hw_loc = ((wid & 1) << 6) + lane;   // 0..127
        const int c0 = (wid >> 1) << 5;               // 0 or 32
        float* ob = outq + ((size_t)n << 16) + hw0 + hw_loc;
#pragma unroll
        for (int j = 0; j < 32; ++j) {
            int c = c0 + j;
            __builtin_nontemporal_store(sm.q[hw_loc * 65 + c],
                                        &ob[(size_t)c << 10]);
        }
    }

    // ---- Phase D: enc rows for this wave's 32 rows, lane-contiguous NT ----
#pragma unroll 2
    for (int rr = 0; rr < 32; ++rr) {
        const int row_loc = wid * 32 + rr;
        const int k = ks[row_loc];
        floatx2* p = enc2 + ((size_t)(rblk + row_loc) << 9) + lane;
        const int tf2 = k >> 1, tc = k & 1;
#pragma unroll
        for (int i = 0; i < 8; ++i) {           // f2 index lane + 64*i
            floatx2 zv = {0.f, 0.f};
            if (tf2 == lane + (i << 6)) zv[tc] = 1.0f;
            __builtin_nontemporal_store(zv, &p[(size_t)i << 6]);
        }
    }
}

__global__ __launch_bounds__(256) void vq_final_kernel(
    const int* __restrict__ hist, const float* __restrict__ lossacc,
    const float* __restrict__ sumx2, float* __restrict__ out)
{
    const int tid = threadIdx.x;
    float s = 0.f;
    for (int k = tid; k < KCB; k += 256) {
        float p = (float)hist[k] * (1.f / 65536.f);
        s += p * logf(p + 1e-10f);
    }
    __shared__ float red[256];
    red[tid] = s;
    __syncthreads();
    for (int st = 128; st > 0; st >>= 1) {
        if (tid < st) red[tid] += red[tid + st];
        __syncthreads();
    }
    if (tid == 0) {
        // mean||x-q||^2 = (sum x^2 + sum d'_min) / numel
        out[0] = 0.25f * (sumx2[0] + lossacc[0]) * (1.f / 4194304.f);
        out[4194305] = expf(-red[0]);
    }
}

extern "C" void kernel_launch(void* const* d_in, const int* in_sizes, int n_in,
                              void* d_out, int out_size, void* d_ws, size_t ws_size,
                              hipStream_t stream) {
    const float* inp = (const float*)d_in[0];
    const float* emb = (const float*)d_in[1];
    float* out = (float*)d_out;

    float* wsf     = (float*)d_ws;
    float* se      = wsf;                     // 1024 f
    int*   hist    = (int*)(wsf + 1024);      // 1024 i
    float* lossacc = wsf + 2048;              // sum d'_min
    float* sumx2   = wsf + 2049;              // sum x^2
    // B-frags in ws, CORRECTLY spaced 32768 floats (128 KB) apart this time
    // (quantized region is no longer safe: mega writes it in Phase E while
    // other blocks still stream B-frags).
    short8* ebh = (short8*)(wsf + 4096);      // 128 KB: floats [4096..36863]
    short8* ebl = (short8*)(wsf + 36864);     // 128 KB: floats [36864..69631]

    float* outq = out + 1;
    float* enc  = out + 4194306;              // 67,108,864 f (256 MB)

    vq_init_kernel <<<4,   256, 0, stream>>>(emb, se, hist, lossacc, sumx2, ebh, ebl);
    vq_mega_kernel <<<512, 256, 0, stream>>>(inp, ebh, ebl, se,
                                             (const float4*)emb, outq,
                                             hist, lossacc, sumx2, (floatx2*)enc);
    vq_final_kernel<<<1,   256, 0, stream>>>(hist, lossacc, sumx2, out);
}